// Round 5
// baseline (302.024 us; speedup 1.0000x reference)
//
#include <hip/hip_runtime.h>

#define NLAYER 4
#define B_ 128
#define D_ 1024
#define H4_ 4096
#define K_ 2048
#define OUTSEC 131072      // 128*1024
#define CH_PER 8           // K chunks (of 64) per WG
#define GP_STRIDE 524288   // 128*4096 floats per partial buffer

typedef float f32x4 __attribute__((ext_vector_type(4)));
typedef _Float16 h8 __attribute__((ext_vector_type(8)));
typedef _Float16 h4 __attribute__((ext_vector_type(4)));

struct ALF { h8 v[4]; };           // A_lo frags [m*2+ks]
struct W4  { f32x4 a, b, c, d; };  // per-lane W chunk: (ks0: j0-3, j4-7)(ks1: j0-3, j4-7)

__device__ __forceinline__ void stage16(const void* gsrc, char* lds_uniform, int lane) {
#if __has_builtin(__builtin_amdgcn_global_load_lds)
  __builtin_amdgcn_global_load_lds((const __attribute__((address_space(1))) void*)gsrc,
                                   (__attribute__((address_space(3))) void*)lds_uniform,
                                   16, 0, 0);
#else
  *(h8*)(lds_uniform + lane * 16) = *(const h8*)gsrc;
#endif
}

// ---------------- prep: split x/h0 to fp16 hi/lo + reorder biases ----------------
__global__ __launch_bounds__(256)
void prep_kernel(const float* __restrict__ x, const float* __restrict__ h0,
                 const float* __restrict__ bih, const float* __restrict__ bhh,
                 _Float16* __restrict__ Ah, _Float16* __restrict__ Al,
                 float* __restrict__ b4)
{
  if (blockIdx.x >= 640) {               // bias reorder: b4[l][u][q] = bih+bhh
    int idx = (blockIdx.x - 640) * 256 + threadIdx.x;   // 16*256 = 4096 = 4L*1024u
    int l = idx >> 10, u = idx & 1023;
    f32x4 r;
#pragma unroll
    for (int q = 0; q < 4; ++q)
      r[q] = bih[l * H4_ + q * D_ + u] + bhh[l * H4_ + q * D_ + u];
    *(f32x4*)(b4 + (size_t)idx * 4) = r;
    return;
  }
  int i = (blockIdx.x * 256 + threadIdx.x) * 4;   // 640*256*4 = 655360 exact
  const float* src;
  int dst;
  if (i < 131072) {                 // x -> layer0 A[:, 0:1024]
    int b = i >> 10, k = i & 1023;
    src = x + i;
    dst = b * K_ + k;
  } else {                          // h0[l] -> A_l[:, 1024:2048]
    int j = i - 131072;
    int l = j >> 17, r = j & 131071;
    int b = r >> 10, k = r & 1023;
    src = h0 + j;
    dst = l * (B_ * K_) + b * K_ + D_ + k;
  }
  f32x4 v = *(const f32x4*)src;
  h4 hi, lo;
#pragma unroll
  for (int j2 = 0; j2 < 4; ++j2) {
    _Float16 h = (_Float16)v[j2];
    hi[j2] = h;
    lo[j2] = (_Float16)((v[j2] - (float)h) * 4096.0f);
  }
  *(h4*)(Ah + dst) = hi;
  *(h4*)(Al + dst) = lo;
}

// ---------------- GEMM partial: K-split x4, W direct-from-global ----------------
__global__ __launch_bounds__(256, 4)
void gemm_part(const float* __restrict__ Wih, const float* __restrict__ Whh,
               const _Float16* __restrict__ Ah, const _Float16* __restrict__ Al,
               float* __restrict__ gp)
{
  __shared__ __align__(16) char smem[32768];   // A_hi dbuf [2][128 rows][64 cols] fp16
  const int tid  = threadIdx.x;
  const int lane = tid & 63;
  const int wid  = tid >> 6;
  const int bidx = blockIdx.x;
  const int s    = bidx & 3;           // k-split id
  const int nt   = bidx >> 2;          // n-tile (4 hidden units)
  const int u0   = nt * 4;
  const int k0   = s * 512;

  // --- W direct frag addressing ---
  const int n16 = lane & 15;           // n' = du*4+q
  const int kq  = lane >> 4;
  const int wr  = ((n16 & 3) << 10) + u0 + (n16 >> 2);
  const float* wbase = (s < 2) ? (Wih + k0) : (Whh + (k0 - 1024));
  const float* wp = wbase + (size_t)wr * D_ + kq * 8;

  // --- A_hi staging: linear LDS dest, pre-swizzled global source ---
  const int R0   = wid * 32 + (lane >> 3);
  const int cswz = ((lane & 7) ^ (lane >> 3)) * 8;
  const _Float16* ahg = Ah + (size_t)R0 * K_ + k0 + cswz;

  // --- fragment read offsets ---
  const int arow = wid * 32 + n16;
  const int aswz = (lane & 7) << 4;
  const _Float16* alg = Al + (size_t)arow * K_ + k0 + kq * 8;

  f32x4 acc_h[2] = {{0.f,0.f,0.f,0.f},{0.f,0.f,0.f,0.f}};
  f32x4 acc_s[2] = {{0.f,0.f,0.f,0.f},{0.f,0.f,0.f,0.f}};

  auto loadW = [&](int t) -> W4 {
    const float* p = wp + t * 64;
    W4 r;
    r.a = *(const f32x4*)(p);
    r.b = *(const f32x4*)(p + 4);
    r.c = *(const f32x4*)(p + 32);
    r.d = *(const f32x4*)(p + 36);
    return r;
  };
  auto stageA = [&](int t, int buf) {
    const _Float16* g = ahg + t * 64;
    char* lb = smem + buf * 16384 + wid * 4096;
    stage16(g,            lb,        lane);
    stage16(g +  8 * K_,  lb + 1024, lane);
    stage16(g + 16 * K_,  lb + 2048, lane);
    stage16(g + 24 * K_,  lb + 3072, lane);
  };
  auto loadAL = [&](int t) -> ALF {
    ALF r;
#pragma unroll
    for (int m = 0; m < 2; ++m)
#pragma unroll
      for (int ks = 0; ks < 2; ++ks)
        r.v[m * 2 + ks] = *(const h8*)(alg + (size_t)m * 16 * K_ + t * 64 + ks * 32);
    return r;
  };

  // prologue
  W4  wreg = loadW(0);
  ALF alf[2];
  alf[0] = loadAL(0);
  stageA(0, 0);
  __syncthreads();

#pragma unroll
  for (int t = 0; t < CH_PER; ++t) {
    // convert this chunk's W (regs already arrived; drained at the barrier above)
    h8 whi[2], wlo[2];
    {
      const f32x4* wv = &wreg.a;
#pragma unroll
      for (int ks = 0; ks < 2; ++ks)
#pragma unroll
        for (int j = 0; j < 8; ++j) {
          float f = wv[ks * 2 + (j >> 2)][j & 3];
          _Float16 h = (_Float16)f;
          whi[ks][j] = h;
          wlo[ks][j] = (_Float16)((f - (float)h) * 4096.0f);  // scaled: no fp16 denormals
        }
    }
    // issue next chunk's loads before the MFMAs
    if (t + 1 < CH_PER) {
      stageA(t + 1, (t + 1) & 1);
      alf[(t + 1) & 1] = loadAL(t + 1);
      wreg = loadW(t + 1);
    }
    // MFMA on current buffer
    {
      const char* ab = smem + (t & 1) * 16384;
      h8 a[2][2];
#pragma unroll
      for (int ks = 0; ks < 2; ++ks)
#pragma unroll
        for (int m = 0; m < 2; ++m)
          a[m][ks] = *(const h8*)(ab + (arow + m * 16) * 128 + ((ks * 64 + kq * 16) ^ aswz));
#pragma unroll
      for (int m = 0; m < 2; ++m)
#pragma unroll
        for (int ks = 0; ks < 2; ++ks) {
          acc_h[m] = __builtin_amdgcn_mfma_f32_16x16x32_f16(a[m][ks],             whi[ks], acc_h[m], 0, 0, 0);
          acc_s[m] = __builtin_amdgcn_mfma_f32_16x16x32_f16(alf[t & 1].v[m*2+ks], whi[ks], acc_s[m], 0, 0, 0);
          acc_s[m] = __builtin_amdgcn_mfma_f32_16x16x32_f16(a[m][ks],             wlo[ks], acc_s[m], 0, 0, 0);
        }
    }
    __syncthreads();
  }

  // epilogue: write fp32 partial tile (no barrier needed)
  const float INV = 1.0f / 4096.0f;
  float* gout = gp + (size_t)s * GP_STRIDE + (size_t)(nt * 16 + n16);
#pragma unroll
  for (int m = 0; m < 2; ++m)
#pragma unroll
    for (int j = 0; j < 4; ++j) {
      int row = wid * 32 + m * 16 + kq * 4 + j;   // C layout: col=lane&15, row=(lane>>4)*4+j
      gout[(size_t)row * H4_] = acc_h[m][j] + acc_s[m][j] * INV;
    }
}

// ---------------- cell: sum partials + LSTM nonlinearity ----------------
__global__ __launch_bounds__(256)
void cell_kernel(const float* __restrict__ gp, const float* __restrict__ b4,
                 const float* __restrict__ c0, float* __restrict__ out,
                 _Float16* __restrict__ AhN, _Float16* __restrict__ AlN, int layer)
{
  int i = blockIdx.x * 256 + threadIdx.x;   // 512*256 = 131072
  int row = i >> 10, u = i & 1023;
  int c4 = ((u >> 2) << 4) + ((u & 3) << 2);
  const float* g0 = gp + (size_t)row * H4_ + c4;
  f32x4 g = *(const f32x4*)(g0);
  g += *(const f32x4*)(g0 + GP_STRIDE);
  g += *(const f32x4*)(g0 + 2 * (size_t)GP_STRIDE);
  g += *(const f32x4*)(g0 + 3 * (size_t)GP_STRIDE);
  f32x4 bb = *(const f32x4*)(b4 + (size_t)u * 4);
  // q = 0,1,2,3 -> i, f, g, o
  float gi = g[0] + bb[0];
  float gf = g[1] + bb[1];
  float gg = g[2] + bb[2];
  float go = g[3] + bb[3];
  float iv = 1.0f / (1.0f + __expf(-gi));
  float fv = 1.0f / (1.0f + __expf(-gf));
  float gv = tanhf(gg);
  float ov = 1.0f / (1.0f + __expf(-go));
  float c0v = c0[i];
  float c1  = fv * c0v + iv * gv;
  float h1v = ov * tanhf(c1);
  out[(5 + layer) * OUTSEC + i] = c1;
  out[(1 + layer) * OUTSEC + i] = h1v;
  if (layer == 3) {
    out[i] = h1v;
  } else {
    _Float16 hh = (_Float16)h1v;
    AhN[(size_t)row * K_ + u] = hh;
    AlN[(size_t)row * K_ + u] = (_Float16)((h1v - (float)hh) * 4096.0f);
  }
}

// ---------------- host ----------------
extern "C" void kernel_launch(void* const* d_in, const int* in_sizes, int n_in,
                              void* d_out, int out_size, void* d_ws, size_t ws_size,
                              hipStream_t stream)
{
  const float* x   = (const float*)d_in[0];
  const float* h0  = (const float*)d_in[1];
  const float* c0  = (const float*)d_in[2];
  const float* Wih = (const float*)d_in[3];
  const float* Whh = (const float*)d_in[4];
  const float* bih = (const float*)d_in[5];
  const float* bhh = (const float*)d_in[6];
  float* out = (float*)d_out;

  _Float16* Ah = (_Float16*)d_ws;                         // [4][128][2048] hi  (2 MB)
  _Float16* Al = Ah + 4 * B_ * K_;                        // lo                 (2 MB)
  float* gp = (float*)((char*)d_ws + 4u * 1024 * 1024);   // [4][128][4096] f32 (8 MB)
  float* b4 = (float*)((char*)d_ws + 12u * 1024 * 1024);  // [4][1024][4] f32   (64 KB)

  prep_kernel<<<656, 256, 0, stream>>>(x, h0, bih, bhh, Ah, Al, b4);
  for (int l = 0; l < NLAYER; ++l) {
    gemm_part<<<1024, 256, 0, stream>>>(
        Wih + (size_t)l * H4_ * D_, Whh + (size_t)l * H4_ * D_,
        Ah + (size_t)l * B_ * K_, Al + (size_t)l * B_ * K_, gp);
    cell_kernel<<<512, 256, 0, stream>>>(
        gp, b4 + (size_t)l * 4096, c0 + (size_t)l * OUTSEC, out,
        (l < 3) ? Ah + (size_t)(l + 1) * B_ * K_ : (_Float16*)nullptr,
        (l < 3) ? Al + (size_t)(l + 1) * B_ * K_ : (_Float16*)nullptr, l);
  }
}

// Round 7
// 280.487 us; speedup vs baseline: 1.0768x; 1.0768x over previous
//
#include <hip/hip_runtime.h>

#define NLAYER 4
#define B_ 128
#define D_ 1024
#define H4_ 4096
#define K_ 2048
#define OUTSEC 131072        // 128*1024
#define GP_STRIDE 524288     // floats per k-split partial buffer (128*4096)
#define AL_STRIDE 262144     // halves per layer of frag-major A (128*2048)

typedef float f32x4 __attribute__((ext_vector_type(4)));
typedef _Float16 h8 __attribute__((ext_vector_type(8)));
typedef _Float16 h4 __attribute__((ext_vector_type(4)));

// Fragment-major A layout: frag = 16 rows x 32 k (512 elems, 1KB); within a frag,
// lane slot = ((k>>3)&3)*16 + (row&15) == lane, so a wave's MFMA A-fragment load is
// ONE contiguous 1KB read at base + lane*16B.
__device__ __forceinline__ int amoff(int row, int k) {
  return ((k >> 5) * 8 + (row >> 4)) * 512 + (((k >> 3) & 3) * 16 + (row & 15)) * 8 + (k & 7);
}

// ---------------- prep: x/h0 -> fp16 hi/lo frag-major A; bias combine ----------------
__global__ __launch_bounds__(256)
void prep_kernel(const float* __restrict__ x, const float* __restrict__ h0,
                 const float* __restrict__ bih, const float* __restrict__ bhh,
                 _Float16* __restrict__ Ah, _Float16* __restrict__ Al,
                 float* __restrict__ b4)
{
  if (blockIdx.x >= 640) {               // bias reorder: b4[l][u][q] = bih+bhh
    int idx = (blockIdx.x - 640) * 256 + threadIdx.x;   // 0..4095 = 4L x 1024u
    int l = idx >> 10, u = idx & 1023;
    f32x4 r;
#pragma unroll
    for (int q = 0; q < 4; ++q)
      r[q] = bih[l * H4_ + q * D_ + u] + bhh[l * H4_ + q * D_ + u];
    *(f32x4*)(b4 + (size_t)idx * 4) = r;
    return;
  }
  int i = (blockIdx.x * 256 + threadIdx.x) * 4;   // 640*256*4 = 655360 exact
  const float* src;
  int l, row, k;
  if (i < 131072) {                 // x -> layer0 A[:, 0:1024]
    l = 0; row = i >> 10; k = i & 1023;
    src = x + i;
  } else {                          // h0[l] -> A_l[:, 1024:2048]
    int j = i - 131072;
    l = j >> 17;
    int r = j & 131071;
    row = r >> 10; k = (r & 1023) + D_;
    src = h0 + j;
  }
  f32x4 v = *(const f32x4*)src;
  h4 hi, lo;
#pragma unroll
  for (int j2 = 0; j2 < 4; ++j2) {
    _Float16 h = (_Float16)v[j2];
    hi[j2] = h;
    lo[j2] = (_Float16)((v[j2] - (float)h) * 4096.0f);   // scaled: avoids fp16 denormals
  }
  int off = l * AL_STRIDE + amoff(row, k);   // (k&7) in {0,4}: h4 fits one 8-elem slot
  *(h4*)(Ah + off) = hi;
  *(h4*)(Al + off) = lo;
}

// ---------------- GEMM partial: barrier-free, frag-major A, W direct ----------------
__global__ __launch_bounds__(256, 4)
void gemm_part(const float* __restrict__ Wih, const float* __restrict__ Whh,
               const _Float16* __restrict__ Ah, const _Float16* __restrict__ Al,
               float* __restrict__ gp)
{
  const int tid  = threadIdx.x;
  const int lane = tid & 63;
  const int wid  = tid >> 6;
  const int s    = blockIdx.x & 3;     // k-split id (K window of 512)
  const int nt   = blockIdx.x >> 2;    // n-tile (4 hidden units = 16 gate cols)
  const int u0   = nt * 4;
  const int k0   = s * 512;

  // W direct per-lane fragment addressing (B-operand: col=lane&15, k=(lane>>4)*8+j)
  const int n16 = lane & 15;           // du*4 + q
  const int kq  = lane >> 4;
  const int wr  = ((n16 & 3) << 10) + u0 + (n16 >> 2);
  const float* wbase = (s < 2) ? (Wih + k0) : (Whh + (k0 - 1024));
  const float* wp = wbase + (size_t)wr * D_ + kq * 8;

  // Frag-major A per-lane base: byte = (s*16 kfrags)*8192 + (rowblock wid*2)*1024 + lane*16
  const char* afh0 = (const char*)Ah + (size_t)(s * 16) * 8192 + (wid * 2) * 1024 + lane * 16;
  const char* afl0 = (const char*)Al + (size_t)(s * 16) * 8192 + (wid * 2) * 1024 + lane * 16;

  f32x4 acc_h[2] = {{0.f,0.f,0.f,0.f},{0.f,0.f,0.f,0.f}};
  f32x4 acc_s[2] = {{0.f,0.f,0.f,0.f},{0.f,0.f,0.f,0.f}};

  // 8 chunks of K=64; NO barriers, NO LDS — latency hides via TLP + free compiler hoisting
  for (int t = 0; t < 8; ++t) {
    const float* p = wp + t * 64;
    f32x4 w0 = *(const f32x4*)(p);          // ks0 j0-3
    f32x4 w1 = *(const f32x4*)(p + 4);      // ks0 j4-7
    f32x4 w2 = *(const f32x4*)(p + 32);     // ks1 j0-3
    f32x4 w3 = *(const f32x4*)(p + 36);     // ks1 j4-7
    h8 ah[2][2], al[2][2];
#pragma unroll
    for (int ks = 0; ks < 2; ++ks)
#pragma unroll
      for (int m = 0; m < 2; ++m) {
        int bo = (t * 2 + ks) * 8192 + m * 1024;
        ah[m][ks] = *(const h8*)(afh0 + bo);
        al[m][ks] = *(const h8*)(afl0 + bo);
      }
#pragma unroll
    for (int ks = 0; ks < 2; ++ks) {
      h8 whi, wlo;
#pragma unroll
      for (int j = 0; j < 8; ++j) {
        float f = (j < 4) ? (ks ? w2[j] : w0[j]) : (ks ? w3[j - 4] : w1[j - 4]);
        _Float16 h = (_Float16)f;
        whi[j] = h;
        wlo[j] = (_Float16)((f - (float)h) * 4096.0f);  // scaled: no fp16 denormals
      }
#pragma unroll
      for (int m = 0; m < 2; ++m) {
        acc_h[m] = __builtin_amdgcn_mfma_f32_16x16x32_f16(ah[m][ks], whi, acc_h[m], 0, 0, 0);
        acc_s[m] = __builtin_amdgcn_mfma_f32_16x16x32_f16(al[m][ks], whi, acc_s[m], 0, 0, 0);
        acc_s[m] = __builtin_amdgcn_mfma_f32_16x16x32_f16(ah[m][ks], wlo, acc_s[m], 0, 0, 0);
      }
    }
  }

  // write fp32 partial tile (C layout: col=lane&15, row=(lane>>4)*4+j)
  const float INV = 1.0f / 4096.0f;
  float* gout = gp + (size_t)s * GP_STRIDE + nt * 16 + n16;
#pragma unroll
  for (int m = 0; m < 2; ++m)
#pragma unroll
    for (int j = 0; j < 4; ++j) {
      int row = wid * 32 + m * 16 + kq * 4 + j;
      gout[(size_t)row * H4_] = acc_h[m][j] + acc_s[m][j] * INV;
    }
}

// ---------------- cell: sum partials + LSTM nonlinearity (round-5-proven) ----------------
__global__ __launch_bounds__(256)
void cell_kernel(const float* __restrict__ gp, const float* __restrict__ b4,
                 const float* __restrict__ c0, float* __restrict__ out,
                 _Float16* __restrict__ AhN, _Float16* __restrict__ AlN, int layer)
{
  int i = blockIdx.x * 256 + threadIdx.x;   // 512*256 = 131072
  int row = i >> 10, u = i & 1023;
  int c4 = ((u >> 2) << 4) + ((u & 3) << 2);
  const float* g0 = gp + (size_t)row * H4_ + c4;
  f32x4 g = *(const f32x4*)(g0);
  g += *(const f32x4*)(g0 + GP_STRIDE);
  g += *(const f32x4*)(g0 + 2 * (size_t)GP_STRIDE);
  g += *(const f32x4*)(g0 + 3 * (size_t)GP_STRIDE);
  f32x4 bb = *(const f32x4*)(b4 + (size_t)u * 4);
  // q = 0,1,2,3 -> i, f, g, o
  float gi = g[0] + bb[0];
  float gf = g[1] + bb[1];
  float gg = g[2] + bb[2];
  float go = g[3] + bb[3];
  float iv = 1.0f / (1.0f + __expf(-gi));
  float fv = 1.0f / (1.0f + __expf(-gf));
  float gv = tanhf(gg);
  float ov = 1.0f / (1.0f + __expf(-go));
  float c0v = c0[i];
  float c1  = fv * c0v + iv * gv;
  float h1v = ov * tanhf(c1);
  out[(5 + layer) * OUTSEC + i] = c1;
  out[(1 + layer) * OUTSEC + i] = h1v;
  if (layer == 3) {
    out[i] = h1v;
  } else {
    _Float16 hh = (_Float16)h1v;
    int off = amoff(row, u);                 // h -> next layer cols 0..1023, frag-major
    AhN[off] = hh;
    AlN[off] = (_Float16)((h1v - (float)hh) * 4096.0f);
  }
}

// ---------------- host ----------------
extern "C" void kernel_launch(void* const* d_in, const int* in_sizes, int n_in,
                              void* d_out, int out_size, void* d_ws, size_t ws_size,
                              hipStream_t stream)
{
  const float* x   = (const float*)d_in[0];
  const float* h0  = (const float*)d_in[1];
  const float* c0  = (const float*)d_in[2];
  const float* Wih = (const float*)d_in[3];
  const float* Whh = (const float*)d_in[4];
  const float* bih = (const float*)d_in[5];
  const float* bhh = (const float*)d_in[6];
  float* out = (float*)d_out;

  _Float16* Ah = (_Float16*)d_ws;                          // [4][AL_STRIDE] hi  (2 MB)
  _Float16* Al = Ah + 4 * AL_STRIDE;                       // lo                 (2 MB)
  float* gp = (float*)((char*)d_ws + (4u << 20));          // [4][128][4096] f32 (8 MB)
  float* b4 = (float*)((char*)d_ws + (12u << 20));         // [4][1024][4] f32   (64 KB)

  prep_kernel<<<656, 256, 0, stream>>>(x, h0, bih, bhh, Ah, Al, b4);
  for (int l = 0; l < NLAYER; ++l) {
    gemm_part<<<1024, 256, 0, stream>>>(
        Wih + (size_t)l * H4_ * D_, Whh + (size_t)l * H4_ * D_,
        Ah + (size_t)l * AL_STRIDE, Al + (size_t)l * AL_STRIDE, gp);
    cell_kernel<<<512, 256, 0, stream>>>(
        gp, b4 + (size_t)l * 4096, c0 + (size_t)l * OUTSEC, out,
        (l < 3) ? Ah + (size_t)(l + 1) * AL_STRIDE : (_Float16*)nullptr,
        (l < 3) ? Al + (size_t)(l + 1) * AL_STRIDE : (_Float16*)nullptr, l);
  }
}

// Round 13
// 259.257 us; speedup vs baseline: 1.1650x; 1.0819x over previous
//
#include <hip/hip_runtime.h>

#define NLAYER 4
#define B_ 128
#define D_ 1024
#define H4_ 4096
#define K_ 2048
#define OUTSEC 131072        // 128*1024
#define KSPLIT 8
#define GP_STRIDE 524288     // floats per k-split partial buffer (128*4096)
#define AL_STRIDE 262144     // halves per layer of frag-major A (128*2048)

typedef float f32x4 __attribute__((ext_vector_type(4)));
typedef _Float16 h8 __attribute__((ext_vector_type(8)));
typedef _Float16 h4 __attribute__((ext_vector_type(4)));

// Fragment-major A layout: frag = 16 rows x 32 k (512 elems, 1KB); within a frag,
// lane slot = ((k>>3)&3)*16 + (row&15) == lane, so a wave's MFMA A-fragment load is
// ONE contiguous 1KB read at base + lane*16B.
__device__ __forceinline__ int amoff(int row, int k) {
  return ((k >> 5) * 8 + (row >> 4)) * 512 + (((k >> 3) & 3) * 16 + (row & 15)) * 8 + (k & 7);
}

// ---------------- prep: x/h0 -> fp16 frag-major A; bias combine ----------------
__global__ __launch_bounds__(256)
void prep_kernel(const float* __restrict__ x, const float* __restrict__ h0,
                 const float* __restrict__ bih, const float* __restrict__ bhh,
                 _Float16* __restrict__ Ah, float* __restrict__ b4)
{
  if (blockIdx.x >= 640) {               // bias reorder: b4[l][u][q] = bih+bhh
    int idx = (blockIdx.x - 640) * 256 + threadIdx.x;   // 0..4095 = 4L x 1024u
    int l = idx >> 10, u = idx & 1023;
    f32x4 r;
#pragma unroll
    for (int q = 0; q < 4; ++q)
      r[q] = bih[l * H4_ + q * D_ + u] + bhh[l * H4_ + q * D_ + u];
    *(f32x4*)(b4 + (size_t)idx * 4) = r;
    return;
  }
  int i = (blockIdx.x * 256 + threadIdx.x) * 4;   // 640*256*4 = 655360 exact
  const float* src;
  int l, row, k;
  if (i < 131072) {                 // x -> layer0 A[:, 0:1024]
    l = 0; row = i >> 10; k = i & 1023;
    src = x + i;
  } else {                          // h0[l] -> A_l[:, 1024:2048]
    int j = i - 131072;
    l = j >> 17;
    int r = j & 131071;
    row = r >> 10; k = (r & 1023) + D_;
    src = h0 + j;
  }
  f32x4 v = *(const f32x4*)src;
  h4 hi;
#pragma unroll
  for (int j2 = 0; j2 < 4; ++j2) hi[j2] = (_Float16)v[j2];   // RNE, 1 cvt each
  *(h4*)(Ah + l * AL_STRIDE + amoff(row, k)) = hi;   // (k&7) in {0,4}: h4 = one slot
}

// ---------------- GEMM partial: barrier-free, single-fp16, 8-way K-split ----------------
__global__ __launch_bounds__(256, 8)
void gemm_part(const float* __restrict__ Wih, const float* __restrict__ Whh,
               const _Float16* __restrict__ Ah, float* __restrict__ gp)
{
  const int tid  = threadIdx.x;
  const int lane = tid & 63;
  const int wid  = tid >> 6;
  const int s    = blockIdx.x & 7;     // k-split id (K window of 256)
  const int nt   = blockIdx.x >> 3;    // n-tile (4 hidden units = 16 gate cols)
  const int u0   = nt * 4;
  const int k0   = s * 256;

  // W direct per-lane fragment addressing (B-operand: col=lane&15, k=(lane>>4)*8+j)
  const int n16 = lane & 15;           // du*4 + q
  const int kq  = lane >> 4;
  const int wr  = ((n16 & 3) << 10) + u0 + (n16 >> 2);
  const float* wbase = (s < 4) ? (Wih + k0) : (Whh + (k0 - 1024));
  const float* wp = wbase + (size_t)wr * D_ + kq * 8;

  // Frag-major A per-lane base: byte = (s*8 kfrags)*8192 + (rowblock wid*2)*1024 + lane*16
  const char* afh0 = (const char*)Ah + (size_t)s * 65536 + (wid * 2) * 1024 + lane * 16;

  f32x4 acc[2] = {{0.f,0.f,0.f,0.f},{0.f,0.f,0.f,0.f}};

  // 4 chunks of K=64; NO barriers, NO LDS — latency hides via 32 waves/CU TLP
  for (int t = 0; t < 4; ++t) {
    const float* p = wp + t * 64;
    f32x4 w0 = *(const f32x4*)(p);          // ks0 j0-3
    f32x4 w1 = *(const f32x4*)(p + 4);      // ks0 j4-7
    f32x4 w2 = *(const f32x4*)(p + 32);     // ks1 j0-3
    f32x4 w3 = *(const f32x4*)(p + 36);     // ks1 j4-7
    h8 ah[2][2];
#pragma unroll
    for (int ks = 0; ks < 2; ++ks)
#pragma unroll
      for (int m = 0; m < 2; ++m)
        ah[m][ks] = *(const h8*)(afh0 + (t * 2 + ks) * 8192 + m * 1024);
#pragma unroll
    for (int ks = 0; ks < 2; ++ks) {
      h8 whi;
#pragma unroll
      for (int j = 0; j < 8; ++j) {
        float f = (j < 4) ? (ks ? w2[j] : w0[j]) : (ks ? w3[j - 4] : w1[j - 4]);
        whi[j] = (_Float16)f;               // one v_cvt_f16_f32 (RNE)
      }
#pragma unroll
      for (int m = 0; m < 2; ++m)
        acc[m] = __builtin_amdgcn_mfma_f32_16x16x32_f16(ah[m][ks], whi, acc[m], 0, 0, 0);
    }
  }

  // write fp32 partial tile (C layout: col=lane&15, row=(lane>>4)*4+j)
  float* gout = gp + (size_t)s * GP_STRIDE + nt * 16 + n16;
#pragma unroll
  for (int m = 0; m < 2; ++m)
#pragma unroll
    for (int j = 0; j < 4; ++j) {
      int row = wid * 32 + m * 16 + kq * 4 + j;
      gout[(size_t)row * H4_] = acc[m][j];
    }
}

// ---------------- cell: sum 8 partials + LSTM nonlinearity ----------------
__global__ __launch_bounds__(256)
void cell_kernel(const float* __restrict__ gp, const float* __restrict__ b4,
                 const float* __restrict__ c0, float* __restrict__ out,
                 _Float16* __restrict__ AhN, int layer)
{
  int i = blockIdx.x * 256 + threadIdx.x;   // 512*256 = 131072
  int row = i >> 10, u = i & 1023;
  int c4 = ((u >> 2) << 4) + ((u & 3) << 2);
  const float* g0 = gp + (size_t)row * H4_ + c4;
  f32x4 g = *(const f32x4*)(g0);
#pragma unroll
  for (int ss = 1; ss < KSPLIT; ++ss)
    g += *(const f32x4*)(g0 + (size_t)ss * GP_STRIDE);
  f32x4 bb = *(const f32x4*)(b4 + (size_t)u * 4);
  // q = 0,1,2,3 -> i, f, g, o
  float gi = g[0] + bb[0];
  float gf = g[1] + bb[1];
  float gg = g[2] + bb[2];
  float go = g[3] + bb[3];
  float iv = 1.0f / (1.0f + __expf(-gi));
  float fv = 1.0f / (1.0f + __expf(-gf));
  float gv = tanhf(gg);
  float ov = 1.0f / (1.0f + __expf(-go));
  float c0v = c0[i];
  float c1  = fv * c0v + iv * gv;
  float h1v = ov * tanhf(c1);
  out[(5 + layer) * OUTSEC + i] = c1;
  out[(1 + layer) * OUTSEC + i] = h1v;
  if (layer == 3) {
    out[i] = h1v;
  } else {
    AhN[amoff(row, u)] = (_Float16)h1v;      // h -> next layer cols 0..1023, frag-major
  }
}

// ---------------- host ----------------
extern "C" void kernel_launch(void* const* d_in, const int* in_sizes, int n_in,
                              void* d_out, int out_size, void* d_ws, size_t ws_size,
                              hipStream_t stream)
{
  const float* x   = (const float*)d_in[0];
  const float* h0  = (const float*)d_in[1];
  const float* c0  = (const float*)d_in[2];
  const float* Wih = (const float*)d_in[3];
  const float* Whh = (const float*)d_in[4];
  const float* bih = (const float*)d_in[5];
  const float* bhh = (const float*)d_in[6];
  float* out = (float*)d_out;

  _Float16* Ah = (_Float16*)d_ws;                          // [4][AL_STRIDE] fp16  (2 MB)
  float* gp = (float*)((char*)d_ws + (2u << 20));          // [8][128][4096] f32   (16 MB)
  float* b4 = (float*)((char*)d_ws + (18u << 20));         // [4][1024][4] f32     (64 KB)

  prep_kernel<<<656, 256, 0, stream>>>(x, h0, bih, bhh, Ah, b4);
  for (int l = 0; l < NLAYER; ++l) {
    gemm_part<<<2048, 256, 0, stream>>>(
        Wih + (size_t)l * H4_ * D_, Whh + (size_t)l * H4_ * D_,
        Ah + (size_t)l * AL_STRIDE, gp);
    cell_kernel<<<512, 256, 0, stream>>>(
        gp, b4 + (size_t)l * 4096, c0 + (size_t)l * OUTSEC, out,
        (l < 3) ? Ah + (size_t)(l + 1) * AL_STRIDE : (_Float16*)nullptr, l);
  }
}